// Round 11
// baseline (184.674 us; speedup 1.0000x reference)
//
#include <hip/hip_runtime.h>

#define N_POINTS 500000
#define K_CENT   512
#define W_DIM    64
#define N_JOBS   ((N_POINTS + 63) / 64)   // 7813 (last job: 32 valid points)

typedef _Float16 half8 __attribute__((ext_vector_type(8)));
typedef float    f32x4 __attribute__((ext_vector_type(4)));

// ---- pre-kernel 1: codebook -> 16x16x32-fragment-ordered f16 hi/lo of w=-2c.
// Layout: [t:16][plane:2][csub:2][kstep:2][lane:64][j:8] -> 8 KB/chunk.
// A-frag (mfma_f32_16x16x32_f16, M=16cent K=32dim): lane l holds
// row = l&15 (cent in csub), k = (l>>4)*8+j (dim in kstep).
// => cent c = t*32 + csub*16 + (l&15), dim d = kstep*32 + (l>>4)*8 + j.
// lo plane = unscaled residual (verified R8).
__global__ void cvt_kernel(const float* __restrict__ cb,
                           _Float16* __restrict__ cbf) {
    int id = blockIdx.x * 256 + threadIdx.x;           // 4096 ids
    if (id >= K_CENT * 8) return;
    int c = id >> 3, o = (id & 7) * 8;                 // centroid, dim base
    int t = c >> 5, csub = (c >> 4) & 1, r = c & 15;
    int kstep = o >> 5, grp = (o >> 3) & 3;
    int lane = grp * 16 + r;
    const float* src = cb + (size_t)c * W_DIM + o;
    half8 h, l;
#pragma unroll
    for (int j = 0; j < 8; ++j) {
        float w = -2.0f * src[j];
        _Float16 hh = (_Float16)w;                     // RNE
        h[j] = hh;
        l[j] = (_Float16)(w - (float)hh);              // unscaled residual
    }
    size_t bh = ((((size_t)t * 2 + 0) * 2 + csub) * 2 + kstep) * 512 + (size_t)lane * 8;
    size_t bl = ((((size_t)t * 2 + 1) * 2 + csub) * 2 + kstep) * 512 + (size_t)lane * 8;
    *(half8*)(cbf + bh) = h;
    *(half8*)(cbf + bl) = l;
}

// ---- pre-kernel 2: c2[c] = ||c||^2 in double (deterministic)
__global__ void c2_kernel(const float* __restrict__ cb, float* __restrict__ c2) {
    int c = blockIdx.x * 256 + threadIdx.x;
    if (c >= K_CENT) return;
    const float4* row = (const float4*)(cb + (size_t)c * W_DIM);
    double s = 0.0;
#pragma unroll
    for (int j = 0; j < W_DIM / 4; ++j) {
        float4 v = row[j];
        s += (double)v.x * v.x + (double)v.y * v.y + (double)v.z * v.z + (double)v.w * v.w;
    }
    c2[c] = (float)s;
}

#define MFMA16(A, B, C) __builtin_amdgcn_mfma_f32_16x16x32_f16(A, B, C, 0, 0, 0)

// Prefetch chunk T's 8 A-fragments into the given (named) buffer set.
#define PREFETCH_A(T, DH, DL)                                                  \
    {                                                                          \
        const _Float16* nb = cbf + (size_t)(T) * 4096 + (size_t)lane * 8;      \
        DH[0][0] = *(const half8*)(nb + 0 * 512);                              \
        DH[0][1] = *(const half8*)(nb + 1 * 512);                              \
        DH[1][0] = *(const half8*)(nb + 2 * 512);                              \
        DH[1][1] = *(const half8*)(nb + 3 * 512);                              \
        DL[0][0] = *(const half8*)(nb + 2048 + 0 * 512);                       \
        DL[0][1] = *(const half8*)(nb + 2048 + 1 * 512);                       \
        DL[1][0] = *(const half8*)(nb + 2048 + 2 * 512);                       \
        DL[1][1] = *(const half8*)(nb + 2048 + 3 * 512);                       \
    }

// Chunk T: 48 MFMAs as 16 INDEPENDENT 3-deep chains (accA/accB[cs][ps]):
// chain (cs,ps,kstep): step0 hi*hi (C-in: q or zro), step1 lo_w*hi_x,
// step2 hi_w*lo_x. Same-chain ops spaced 16 issue slots -> covers dep latency.
// Prefetches A(T+1) first (consumed next chunk); q(T+1) reloaded after the
// MFMA block (WAR-safe: q read at step0 issue), covered by argmin.
#define CHUNK(T, AH, AL, NXH, NXL)                                             \
    {                                                                          \
        int t_ = (T);                                                          \
        if (t_ < 15) { PREFETCH_A(t_ + 1, NXH, NXL) }                          \
        _Pragma("unroll")                                                      \
        for (int cs = 0; cs < 2; ++cs) {                                       \
            _Pragma("unroll")                                                  \
            for (int ps = 0; ps < 4; ++ps)                                     \
                accA[cs][ps] = MFMA16(AH[cs][0], bh[ps][0], cs ? q1 : q0);     \
        }                                                                      \
        _Pragma("unroll")                                                      \
        for (int cs = 0; cs < 2; ++cs) {                                       \
            _Pragma("unroll")                                                  \
            for (int ps = 0; ps < 4; ++ps)                                     \
                accB[cs][ps] = MFMA16(AH[cs][1], bh[ps][1], zro4);             \
        }                                                                      \
        _Pragma("unroll")                                                      \
        for (int cs = 0; cs < 2; ++cs) {                                       \
            _Pragma("unroll")                                                  \
            for (int ps = 0; ps < 4; ++ps)                                     \
                accA[cs][ps] = MFMA16(AL[cs][0], bh[ps][0], accA[cs][ps]);     \
        }                                                                      \
        _Pragma("unroll")                                                      \
        for (int cs = 0; cs < 2; ++cs) {                                       \
            _Pragma("unroll")                                                  \
            for (int ps = 0; ps < 4; ++ps)                                     \
                accB[cs][ps] = MFMA16(AL[cs][1], bh[ps][1], accB[cs][ps]);     \
        }                                                                      \
        _Pragma("unroll")                                                      \
        for (int cs = 0; cs < 2; ++cs) {                                       \
            _Pragma("unroll")                                                  \
            for (int ps = 0; ps < 4; ++ps)                                     \
                accA[cs][ps] = MFMA16(AH[cs][0], bl[ps][0], accA[cs][ps]);     \
        }                                                                      \
        _Pragma("unroll")                                                      \
        for (int cs = 0; cs < 2; ++cs) {                                       \
            _Pragma("unroll")                                                  \
            for (int ps = 0; ps < 4; ++ps)                                     \
                accB[cs][ps] = MFMA16(AH[cs][1], bl[ps][1], accB[cs][ps]);     \
        }                                                                      \
        if (t_ < 15) {                                                         \
            q0 = *(const f32x4*)&c2s[(t_ + 1) * 32 + 0 * 16 + grp4];           \
            q1 = *(const f32x4*)&c2s[(t_ + 1) * 32 + 1 * 16 + grp4];           \
        }                                                                      \
        _Pragma("unroll")                                                      \
        for (int ps = 0; ps < 4; ++ps) {                                       \
            float v0 = accA[0][ps][0] + accB[0][ps][0];                        \
            float v1 = accA[0][ps][1] + accB[0][ps][1];                        \
            float v2 = accA[0][ps][2] + accB[0][ps][2];                        \
            float v3 = accA[0][ps][3] + accB[0][ps][3];                        \
            float v4 = accA[1][ps][0] + accB[1][ps][0];                        \
            float v5 = accA[1][ps][1] + accB[1][ps][1];                        \
            float v6 = accA[1][ps][2] + accB[1][ps][2];                        \
            float v7 = accA[1][ps][3] + accB[1][ps][3];                        \
            float a0 = fminf(v0, v1), a1 = fminf(v2, v3);                      \
            float a2 = fminf(v4, v5), a3 = fminf(v6, v7);                      \
            float b0 = fminf(a0, a1), b1 = fminf(a2, a3);                      \
            float m  = fminf(b0, b1);                                          \
            bool  L2 = (m == b0);                                              \
            float aL = L2 ? a0 : a2;                                           \
            bool  L1 = (m == aL);                                              \
            float vE = L2 ? (L1 ? v0 : v2) : (L1 ? v4 : v6);                   \
            bool  L0 = (m == vE);                                              \
            int ji = (L2 ? 0 : 4) | (L1 ? 0 : 2) | (L0 ? 0 : 1);               \
            int ci = t_ * 32 + (ji >> 2) * 16 + grp4 + (ji & 3);               \
            bool imp = m < bd[ps];                                             \
            bd[ps] = imp ? m : bd[ps];                                         \
            bi[ps] = imp ? ci : bi[ps];                                        \
        }                                                                      \
    }

// ---- main kernel: 4 waves/block, 64 points/wave (4 subtiles of 16).
// 16x16x32 fragments: B col = l&15 (point), k = (l>>4)*8+j (dim).
// C/D: col = l&15 (point), row = (l>>4)*4 + reg (cent in csub) [m89].
__global__ __launch_bounds__(256, 2)
void kmeans_mfma(const float* __restrict__ X,
                 const _Float16* __restrict__ cbf,
                 const float* __restrict__ c2,
                 float* __restrict__ out_idx,
                 float* __restrict__ out_dist) {
    __shared__ __align__(16) float c2s[K_CENT];
    int tid = threadIdx.x;
    c2s[tid] = c2[tid];
    c2s[tid + 256] = c2[tid + 256];
    __syncthreads();

    int wave = tid >> 6;
    int lane = tid & 63;
    int l15  = lane & 15;
    int grp  = lane >> 4;        // 0..3
    int grp4 = grp * 4;
    int grp8 = grp * 8;

    int job = blockIdx.x * 4 + wave;
    if (job >= N_JOBS) return;
    int pbase = job * 64;

    // ---- load + convert X: 4 point-subtiles x 2 K-steps, 8 dims/lane each
    half8 bh[4][2], bl[4][2];
    float x2[4] = {0.f, 0.f, 0.f, 0.f};
    int   pval[4];
#pragma unroll
    for (int ps = 0; ps < 4; ++ps) {
        int p = pbase + ps * 16 + l15;
        pval[ps] = p < N_POINTS;
        int pe = pval[ps] ? p : (N_POINTS - 1);
#pragma unroll
        for (int ks = 0; ks < 2; ++ks) {
            const float4* xp = (const float4*)(X + (size_t)pe * W_DIM + ks * 32 + grp8);
            float4 f0 = xp[0], f1 = xp[1];
            float fa[8] = {f0.x, f0.y, f0.z, f0.w, f1.x, f1.y, f1.z, f1.w};
#pragma unroll
            for (int j = 0; j < 8; ++j) {
                _Float16 hh = (_Float16)fa[j];
                bh[ps][ks][j] = hh;
                bl[ps][ks][j] = (_Float16)(fa[j] - (float)hh);
                x2[ps] = fmaf(fa[j], fa[j], x2[ps]);
            }
        }
    }
#pragma unroll
    for (int ps = 0; ps < 4; ++ps) {    // full ||x||^2 across the 4 row-groups
        x2[ps] += __shfl_xor(x2[ps], 16);
        x2[ps] += __shfl_xor(x2[ps], 32);
    }

    float bd[4] = {3.4e38f, 3.4e38f, 3.4e38f, 3.4e38f};
    int   bi[4] = {0, 0, 0, 0};

    f32x4 zro4 = {0.f, 0.f, 0.f, 0.f};
    f32x4 q0, q1;
    f32x4 accA[2][4], accB[2][4];
    half8 ahA[2][2], alA[2][2], ahB[2][2], alB[2][2];

    PREFETCH_A(0, ahA, alA)
    q0 = *(const f32x4*)&c2s[0 * 16 + grp4];
    q1 = *(const f32x4*)&c2s[1 * 16 + grp4];

#pragma unroll 1
    for (int tt = 0; tt < 8; ++tt) {
        CHUNK(2 * tt,     ahA, alA, ahB, alB)
        CHUNK(2 * tt + 1, ahB, alB, ahA, alA)
    }

    // cross-lane combine over the 4 row-groups (disjoint cents per group);
    // explicit lower-index preference on fp-equal ties.
#pragma unroll
    for (int ps = 0; ps < 4; ++ps) {
        float od = __shfl_xor(bd[ps], 16); int oi = __shfl_xor(bi[ps], 16);
        if (od < bd[ps] || (od == bd[ps] && oi < bi[ps])) { bd[ps] = od; bi[ps] = oi; }
        od = __shfl_xor(bd[ps], 32); oi = __shfl_xor(bi[ps], 32);
        if (od < bd[ps] || (od == bd[ps] && oi < bi[ps])) { bd[ps] = od; bi[ps] = oi; }
    }

    if (grp == 0) {
#pragma unroll
        for (int ps = 0; ps < 4; ++ps) {
            if (pval[ps]) {
                int p = pbase + ps * 16 + l15;
                out_idx[p]  = (float)bi[ps];
                out_dist[p] = sqrtf(fmaxf(bd[ps] + x2[ps], 0.f));
            }
        }
    }
}

extern "C" void kernel_launch(void* const* d_in, const int* in_sizes, int n_in,
                              void* d_out, int out_size, void* d_ws, size_t ws_size,
                              hipStream_t stream) {
    const float* X  = (const float*)d_in[0];
    const float* cb = (const float*)d_in[1];
    float* out      = (float*)d_out;

    // workspace: fragment-ordered codebook 128KB | c2 2KB
    _Float16* cbf = (_Float16*)d_ws;
    float*    c2  = (float*)(cbf + (size_t)K_CENT * W_DIM * 2);

    hipLaunchKernelGGL(cvt_kernel, dim3((K_CENT * 8 + 255) / 256), dim3(256), 0, stream, cb, cbf);
    hipLaunchKernelGGL(c2_kernel, dim3((K_CENT + 255) / 256), dim3(256), 0, stream, cb, c2);

    hipLaunchKernelGGL(kmeans_mfma, dim3((N_JOBS + 3) / 4), dim3(256), 0, stream,
                       X, cbf, c2, out, out + N_POINTS);
}

// Round 12
// 113.007 us; speedup vs baseline: 1.6342x; 1.6342x over previous
//
#include <hip/hip_runtime.h>

#define N_POINTS 500000
#define K_CENT   512
#define W_DIM    64
#define N_SUB    (N_POINTS / 16)          // 31250 exact 16-point subtiles
#define N_JOBS   ((N_SUB + 2) / 3)        // 10417 (last job: 2 valid subtiles)

typedef _Float16 half8 __attribute__((ext_vector_type(8)));
typedef float    f32x4 __attribute__((ext_vector_type(4)));

// ---- pre-kernel 1: codebook -> 16x16x32-fragment-ordered f16 hi/lo of w=-2c.
// Layout: [t:16][plane:2][csub:2][kstep:2][lane:64][j:8] -> 8 KB/chunk.
// A-frag (mfma_f32_16x16x32_f16, M=16cent K=32dim): lane l holds
// row = l&15 (cent in csub), k = (l>>4)*8+j (dim in kstep).
// => cent c = t*32 + csub*16 + (l&15), dim d = kstep*32 + (l>>4)*8 + j.
// lo plane = unscaled residual. (Layout + numerics verified R11: passed.)
__global__ void cvt_kernel(const float* __restrict__ cb,
                           _Float16* __restrict__ cbf) {
    int id = blockIdx.x * 256 + threadIdx.x;           // 4096 ids
    if (id >= K_CENT * 8) return;
    int c = id >> 3, o = (id & 7) * 8;                 // centroid, dim base
    int t = c >> 5, csub = (c >> 4) & 1, r = c & 15;
    int kstep = o >> 5, grp = (o >> 3) & 3;
    int lane = grp * 16 + r;
    const float* src = cb + (size_t)c * W_DIM + o;
    half8 h, l;
#pragma unroll
    for (int j = 0; j < 8; ++j) {
        float w = -2.0f * src[j];
        _Float16 hh = (_Float16)w;                     // RNE
        h[j] = hh;
        l[j] = (_Float16)(w - (float)hh);              // unscaled residual
    }
    size_t bh = ((((size_t)t * 2 + 0) * 2 + csub) * 2 + kstep) * 512 + (size_t)lane * 8;
    size_t bl = ((((size_t)t * 2 + 1) * 2 + csub) * 2 + kstep) * 512 + (size_t)lane * 8;
    *(half8*)(cbf + bh) = h;
    *(half8*)(cbf + bl) = l;
}

// ---- pre-kernel 2: c2[c] = ||c||^2 in double (deterministic)
__global__ void c2_kernel(const float* __restrict__ cb, float* __restrict__ c2) {
    int c = blockIdx.x * 256 + threadIdx.x;
    if (c >= K_CENT) return;
    const float4* row = (const float4*)(cb + (size_t)c * W_DIM);
    double s = 0.0;
#pragma unroll
    for (int j = 0; j < W_DIM / 4; ++j) {
        float4 v = row[j];
        s += (double)v.x * v.x + (double)v.y * v.y + (double)v.z * v.z + (double)v.w * v.w;
    }
    c2[c] = (float)s;
}

#define MFMA16(A, B, C) __builtin_amdgcn_mfma_f32_16x16x32_f16(A, B, C, 0, 0, 0)

// Prefetch chunk T's 8 A-fragments into the given (named) buffer set.
#define PREFETCH_A(T, DH, DL)                                                  \
    {                                                                          \
        const _Float16* nb = cbf + (size_t)(T) * 4096 + (size_t)lane * 8;      \
        DH[0][0] = *(const half8*)(nb + 0 * 512);                              \
        DH[0][1] = *(const half8*)(nb + 1 * 512);                              \
        DH[1][0] = *(const half8*)(nb + 2 * 512);                              \
        DH[1][1] = *(const half8*)(nb + 3 * 512);                              \
        DL[0][0] = *(const half8*)(nb + 2048 + 0 * 512);                       \
        DL[0][1] = *(const half8*)(nb + 2048 + 1 * 512);                       \
        DL[1][0] = *(const half8*)(nb + 2048 + 2 * 512);                       \
        DL[1][1] = *(const half8*)(nb + 2048 + 3 * 512);                       \
    }

// Chunk T: 36 MFMAs as 12 INDEPENDENT 3-deep chains acc{A,B}[cs][ps]
// (A: kstep0, B: kstep1). Chain steps: hi_w*hi_x (C-in q/zro) -> lo_w*hi_x
// -> hi_w*lo_x. Dependent ops spaced 12 issue slots (~233cy) ~ dep latency.
// A(T+1) prefetched first (separate buffer, WAR-free); q(T+1) after MFMAs.
#define CHUNK(T, AH, AL, NXH, NXL)                                             \
    {                                                                          \
        int t_ = (T);                                                          \
        if (t_ < 15) { PREFETCH_A(t_ + 1, NXH, NXL) }                          \
        _Pragma("unroll")                                                      \
        for (int cs = 0; cs < 2; ++cs) {                                       \
            _Pragma("unroll")                                                  \
            for (int ps = 0; ps < 3; ++ps)                                     \
                accA[cs][ps] = MFMA16(AH[cs][0], bh[ps][0], cs ? q1 : q0);     \
        }                                                                      \
        _Pragma("unroll")                                                      \
        for (int cs = 0; cs < 2; ++cs) {                                       \
            _Pragma("unroll")                                                  \
            for (int ps = 0; ps < 3; ++ps)                                     \
                accB[cs][ps] = MFMA16(AH[cs][1], bh[ps][1], zro4);             \
        }                                                                      \
        _Pragma("unroll")                                                      \
        for (int cs = 0; cs < 2; ++cs) {                                       \
            _Pragma("unroll")                                                  \
            for (int ps = 0; ps < 3; ++ps)                                     \
                accA[cs][ps] = MFMA16(AL[cs][0], bh[ps][0], accA[cs][ps]);     \
        }                                                                      \
        _Pragma("unroll")                                                      \
        for (int cs = 0; cs < 2; ++cs) {                                       \
            _Pragma("unroll")                                                  \
            for (int ps = 0; ps < 3; ++ps)                                     \
                accB[cs][ps] = MFMA16(AL[cs][1], bh[ps][1], accB[cs][ps]);     \
        }                                                                      \
        _Pragma("unroll")                                                      \
        for (int cs = 0; cs < 2; ++cs) {                                       \
            _Pragma("unroll")                                                  \
            for (int ps = 0; ps < 3; ++ps)                                     \
                accA[cs][ps] = MFMA16(AH[cs][0], bl[ps][0], accA[cs][ps]);     \
        }                                                                      \
        _Pragma("unroll")                                                      \
        for (int cs = 0; cs < 2; ++cs) {                                       \
            _Pragma("unroll")                                                  \
            for (int ps = 0; ps < 3; ++ps)                                     \
                accB[cs][ps] = MFMA16(AH[cs][1], bl[ps][1], accB[cs][ps]);     \
        }                                                                      \
        if (t_ < 15) {                                                         \
            q0 = *(const f32x4*)&c2s[(t_ + 1) * 32 + 0 * 16 + grp4];           \
            q1 = *(const f32x4*)&c2s[(t_ + 1) * 32 + 1 * 16 + grp4];           \
        }                                                                      \
        _Pragma("unroll")                                                      \
        for (int ps = 0; ps < 3; ++ps) {                                       \
            float v0 = accA[0][ps][0] + accB[0][ps][0];                        \
            float v1 = accA[0][ps][1] + accB[0][ps][1];                        \
            float v2 = accA[0][ps][2] + accB[0][ps][2];                        \
            float v3 = accA[0][ps][3] + accB[0][ps][3];                        \
            float v4 = accA[1][ps][0] + accB[1][ps][0];                        \
            float v5 = accA[1][ps][1] + accB[1][ps][1];                        \
            float v6 = accA[1][ps][2] + accB[1][ps][2];                        \
            float v7 = accA[1][ps][3] + accB[1][ps][3];                        \
            float a0 = fminf(v0, v1), a1 = fminf(v2, v3);                      \
            float a2 = fminf(v4, v5), a3 = fminf(v6, v7);                      \
            float b0 = fminf(a0, a1), b1 = fminf(a2, a3);                      \
            float m  = fminf(b0, b1);                                          \
            bool  L2 = (m == b0);                                              \
            float aL = L2 ? a0 : a2;                                           \
            bool  L1 = (m == aL);                                              \
            float vE = L2 ? (L1 ? v0 : v2) : (L1 ? v4 : v6);                   \
            bool  L0 = (m == vE);                                              \
            int ji = (L2 ? 0 : 4) | (L1 ? 0 : 2) | (L0 ? 0 : 1);               \
            int ci = t_ * 32 + (ji >> 2) * 16 + grp4 + (ji & 3);               \
            bool imp = m < bd[ps];                                             \
            bd[ps] = imp ? m : bd[ps];                                         \
            bi[ps] = imp ? ci : bi[ps];                                        \
        }                                                                      \
    }

// ---- main kernel: 4 waves/block, 48 points/wave (3 subtiles of 16).
// 16x16x32 fragments: B col = l&15 (point), k = (l>>4)*8+j (dim).
// C/D: col = l&15 (point), row = (l>>4)*4 + reg (cent in csub) [m89].
__global__ __launch_bounds__(256, 2)
void kmeans_mfma(const float* __restrict__ X,
                 const _Float16* __restrict__ cbf,
                 const float* __restrict__ c2,
                 float* __restrict__ out_idx,
                 float* __restrict__ out_dist) {
    __shared__ __align__(16) float c2s[K_CENT];
    int tid = threadIdx.x;
    c2s[tid] = c2[tid];
    c2s[tid + 256] = c2[tid + 256];
    __syncthreads();

    int wave = tid >> 6;
    int lane = tid & 63;
    int l15  = lane & 15;
    int grp  = lane >> 4;        // 0..3
    int grp4 = grp * 4;
    int grp8 = grp * 8;

    int job = blockIdx.x * 4 + wave;
    if (job >= N_JOBS) return;
    int sub0 = job * 3;          // first 16-point subtile index

    // ---- load + convert X: 3 point-subtiles x 2 K-steps, 8 dims/lane each
    half8 bh[3][2], bl[3][2];
    float x2[3] = {0.f, 0.f, 0.f};
#pragma unroll
    for (int ps = 0; ps < 3; ++ps) {
        int p = (sub0 + ps) * 16 + l15;
        int pe = p < N_POINTS ? p : (N_POINTS - 1);
#pragma unroll
        for (int ks = 0; ks < 2; ++ks) {
            const float4* xp = (const float4*)(X + (size_t)pe * W_DIM + ks * 32 + grp8);
            float4 f0 = xp[0], f1 = xp[1];
            float fa[8] = {f0.x, f0.y, f0.z, f0.w, f1.x, f1.y, f1.z, f1.w};
#pragma unroll
            for (int j = 0; j < 8; ++j) {
                _Float16 hh = (_Float16)fa[j];
                bh[ps][ks][j] = hh;
                bl[ps][ks][j] = (_Float16)(fa[j] - (float)hh);
                x2[ps] = fmaf(fa[j], fa[j], x2[ps]);
            }
        }
    }
#pragma unroll
    for (int ps = 0; ps < 3; ++ps) {    // full ||x||^2 across the 4 row-groups
        x2[ps] += __shfl_xor(x2[ps], 16);
        x2[ps] += __shfl_xor(x2[ps], 32);
    }

    float bd[3] = {3.4e38f, 3.4e38f, 3.4e38f};
    int   bi[3] = {0, 0, 0};

    f32x4 zro4 = {0.f, 0.f, 0.f, 0.f};
    f32x4 q0, q1;
    f32x4 accA[2][3], accB[2][3];
    half8 ahA[2][2], alA[2][2], ahB[2][2], alB[2][2];

    PREFETCH_A(0, ahA, alA)
    q0 = *(const f32x4*)&c2s[0 * 16 + grp4];
    q1 = *(const f32x4*)&c2s[1 * 16 + grp4];

#pragma unroll 1
    for (int tt = 0; tt < 8; ++tt) {
        CHUNK(2 * tt,     ahA, alA, ahB, alB)
        CHUNK(2 * tt + 1, ahB, alB, ahA, alA)
    }

    // cross-lane combine over the 4 row-groups (disjoint cents per group);
    // explicit lower-index preference on fp-equal ties.
#pragma unroll
    for (int ps = 0; ps < 3; ++ps) {
        float od = __shfl_xor(bd[ps], 16); int oi = __shfl_xor(bi[ps], 16);
        if (od < bd[ps] || (od == bd[ps] && oi < bi[ps])) { bd[ps] = od; bi[ps] = oi; }
        od = __shfl_xor(bd[ps], 32); oi = __shfl_xor(bi[ps], 32);
        if (od < bd[ps] || (od == bd[ps] && oi < bi[ps])) { bd[ps] = od; bi[ps] = oi; }
    }

    if (grp == 0) {
#pragma unroll
        for (int ps = 0; ps < 3; ++ps) {
            int p = (sub0 + ps) * 16 + l15;
            if (p < N_POINTS) {
                out_idx[p]  = (float)bi[ps];
                out_dist[p] = sqrtf(fmaxf(bd[ps] + x2[ps], 0.f));
            }
        }
    }
}

extern "C" void kernel_launch(void* const* d_in, const int* in_sizes, int n_in,
                              void* d_out, int out_size, void* d_ws, size_t ws_size,
                              hipStream_t stream) {
    const float* X  = (const float*)d_in[0];
    const float* cb = (const float*)d_in[1];
    float* out      = (float*)d_out;

    // workspace: fragment-ordered codebook 128KB | c2 2KB
    _Float16* cbf = (_Float16*)d_ws;
    float*    c2  = (float*)(cbf + (size_t)K_CENT * W_DIM * 2);

    hipLaunchKernelGGL(cvt_kernel, dim3((K_CENT * 8 + 255) / 256), dim3(256), 0, stream, cb, cbf);
    hipLaunchKernelGGL(c2_kernel, dim3((K_CENT + 255) / 256), dim3(256), 0, stream, cb, c2);

    hipLaunchKernelGGL(kmeans_mfma, dim3((N_JOBS + 3) / 4), dim3(256), 0, stream,
                       X, cbf, c2, out, out + N_POINTS);
}

// Round 13
// 104.035 us; speedup vs baseline: 1.7751x; 1.0862x over previous
//
#include <hip/hip_runtime.h>

#define N_POINTS 500000
#define K_CENT   512
#define W_DIM    64
#define N_SUB    (N_POINTS / 16)          // 31250 exact 16-point subtiles
#define N_JOBS   ((N_SUB + 2) / 3)        // 10417 (last job: 2 valid subtiles)

typedef _Float16 half8 __attribute__((ext_vector_type(8)));
typedef float    f32x4 __attribute__((ext_vector_type(4)));

// ---- pre-kernel 1: codebook -> 16x16x32-fragment-ordered f16 hi/lo of w=-2c.
// Layout: [t:16][plane:2][csub:2][kstep:2][lane:64][j:8] -> 8 KB/chunk.
// A-frag (mfma_f32_16x16x32_f16): cent c = t*32 + csub*16 + (l&15),
// dim d = kstep*32 + (l>>4)*8 + j. lo = unscaled residual. (Verified R11/R12.)
__global__ void cvt_kernel(const float* __restrict__ cb,
                           _Float16* __restrict__ cbf) {
    int id = blockIdx.x * 256 + threadIdx.x;           // 4096 ids
    if (id >= K_CENT * 8) return;
    int c = id >> 3, o = (id & 7) * 8;                 // centroid, dim base
    int t = c >> 5, csub = (c >> 4) & 1, r = c & 15;
    int kstep = o >> 5, grp = (o >> 3) & 3;
    int lane = grp * 16 + r;
    const float* src = cb + (size_t)c * W_DIM + o;
    half8 h, l;
#pragma unroll
    for (int j = 0; j < 8; ++j) {
        float w = -2.0f * src[j];
        _Float16 hh = (_Float16)w;                     // RNE
        h[j] = hh;
        l[j] = (_Float16)(w - (float)hh);              // unscaled residual
    }
    size_t bh = ((((size_t)t * 2 + 0) * 2 + csub) * 2 + kstep) * 512 + (size_t)lane * 8;
    size_t bl = ((((size_t)t * 2 + 1) * 2 + csub) * 2 + kstep) * 512 + (size_t)lane * 8;
    *(half8*)(cbf + bh) = h;
    *(half8*)(cbf + bl) = l;
}

// ---- pre-kernel 2: c2[c] = ||c||^2 in double (deterministic)
__global__ void c2_kernel(const float* __restrict__ cb, float* __restrict__ c2) {
    int c = blockIdx.x * 256 + threadIdx.x;
    if (c >= K_CENT) return;
    const float4* row = (const float4*)(cb + (size_t)c * W_DIM);
    double s = 0.0;
#pragma unroll
    for (int j = 0; j < W_DIM / 4; ++j) {
        float4 v = row[j];
        s += (double)v.x * v.x + (double)v.y * v.y + (double)v.z * v.z + (double)v.w * v.w;
    }
    c2[c] = (float)s;
}

#define MFMA16(A, B, C) __builtin_amdgcn_mfma_f32_16x16x32_f16(A, B, C, 0, 0, 0)

// Prefetch chunk T's 8 A-fragments into the given (named) buffer set.
#define PREFETCH_A(T, DH, DL)                                                  \
    {                                                                          \
        const _Float16* nb = cbf + (size_t)(T) * 4096 + (size_t)lane * 8;      \
        DH[0][0] = *(const half8*)(nb + 0 * 512);                              \
        DH[0][1] = *(const half8*)(nb + 1 * 512);                              \
        DH[1][0] = *(const half8*)(nb + 2 * 512);                              \
        DH[1][1] = *(const half8*)(nb + 3 * 512);                              \
        DL[0][0] = *(const half8*)(nb + 2048 + 0 * 512);                       \
        DL[0][1] = *(const half8*)(nb + 2048 + 1 * 512);                       \
        DL[1][0] = *(const half8*)(nb + 2048 + 2 * 512);                       \
        DL[1][1] = *(const half8*)(nb + 2048 + 3 * 512);                       \
    }

// MFMA block for chunk T into acc set ACC: 36 MFMAs = 6 chains (cs,ps),
// 6-deep, grouped by step (same-chain ops 6 issue slots apart). C-in = q.
// Also: prefetch A(T+1) into NX* (separate buffer, WAR-free), then reload
// q(T+1) after the MFMA block (WAR-safe: q read at step-0 issue, ~700cy prior).
#define MFMA_CHUNK(T, AH, AL, NXH, NXL, ACC)                                   \
    {                                                                          \
        int t_ = (T);                                                          \
        if (t_ < 15) { PREFETCH_A(t_ + 1, NXH, NXL) }                          \
        _Pragma("unroll")                                                      \
        for (int cs = 0; cs < 2; ++cs)                                         \
            _Pragma("unroll")                                                  \
            for (int ps = 0; ps < 3; ++ps)                                     \
                ACC[cs][ps] = MFMA16(AH[cs][0], bh[ps][0], cs ? q1 : q0);      \
        _Pragma("unroll")                                                      \
        for (int cs = 0; cs < 2; ++cs)                                         \
            _Pragma("unroll")                                                  \
            for (int ps = 0; ps < 3; ++ps)                                     \
                ACC[cs][ps] = MFMA16(AH[cs][1], bh[ps][1], ACC[cs][ps]);       \
        _Pragma("unroll")                                                      \
        for (int cs = 0; cs < 2; ++cs)                                         \
            _Pragma("unroll")                                                  \
            for (int ps = 0; ps < 3; ++ps)                                     \
                ACC[cs][ps] = MFMA16(AL[cs][0], bh[ps][0], ACC[cs][ps]);       \
        _Pragma("unroll")                                                      \
        for (int cs = 0; cs < 2; ++cs)                                         \
            _Pragma("unroll")                                                  \
            for (int ps = 0; ps < 3; ++ps)                                     \
                ACC[cs][ps] = MFMA16(AL[cs][1], bh[ps][1], ACC[cs][ps]);       \
        _Pragma("unroll")                                                      \
        for (int cs = 0; cs < 2; ++cs)                                         \
            _Pragma("unroll")                                                  \
            for (int ps = 0; ps < 3; ++ps)                                     \
                ACC[cs][ps] = MFMA16(AH[cs][0], bl[ps][0], ACC[cs][ps]);       \
        _Pragma("unroll")                                                      \
        for (int cs = 0; cs < 2; ++cs)                                         \
            _Pragma("unroll")                                                  \
            for (int ps = 0; ps < 3; ++ps)                                     \
                ACC[cs][ps] = MFMA16(AH[cs][1], bl[ps][1], ACC[cs][ps]);       \
        if (t_ < 15) {                                                         \
            q0 = *(const f32x4*)&c2s[(t_ + 1) * 32 + 0 * 16 + grp4];           \
            q1 = *(const f32x4*)&c2s[(t_ + 1) * 32 + 1 * 16 + grp4];           \
        }                                                                      \
    }

// Deferred argmin for acc set ACC of chunk T_ (MFMAs finished ~1 chunk ago ->
// no register-dep stall). Binary descent, ties prefer LEFT = lower index.
#define ARGMIN_CHUNK(T_, ACC)                                                  \
    {                                                                          \
        _Pragma("unroll")                                                      \
        for (int ps = 0; ps < 3; ++ps) {                                       \
            float v0 = ACC[0][ps][0], v1 = ACC[0][ps][1];                      \
            float v2 = ACC[0][ps][2], v3 = ACC[0][ps][3];                      \
            float v4 = ACC[1][ps][0], v5 = ACC[1][ps][1];                      \
            float v6 = ACC[1][ps][2], v7 = ACC[1][ps][3];                      \
            float a0 = fminf(v0, v1), a1 = fminf(v2, v3);                      \
            float a2 = fminf(v4, v5), a3 = fminf(v6, v7);                      \
            float b0 = fminf(a0, a1), b1 = fminf(a2, a3);                      \
            float m  = fminf(b0, b1);                                          \
            bool  L2 = (m == b0);                                              \
            float aL = L2 ? a0 : a2;                                           \
            bool  L1 = (m == aL);                                              \
            float vE = L2 ? (L1 ? v0 : v2) : (L1 ? v4 : v6);                   \
            bool  L0 = (m == vE);                                              \
            int ji = (L2 ? 0 : 4) | (L1 ? 0 : 2) | (L0 ? 0 : 1);               \
            int ci = (T_) * 32 + (ji >> 2) * 16 + grp4 + (ji & 3);             \
            bool imp = m < bd[ps];                                             \
            bd[ps] = imp ? m : bd[ps];                                         \
            bi[ps] = imp ? ci : bi[ps];                                        \
        }                                                                      \
    }

// ---- main kernel: 4 waves/block, 48 points/wave (3 subtiles of 16).
// Software pipeline: MFMA(t) issued, THEN argmin(t-1) on the other acc set
// runs entirely under MFMA(t)'s shadow (MFMA/VALU are separate pipes).
__global__ __launch_bounds__(256, 2)
void kmeans_mfma(const float* __restrict__ X,
                 const _Float16* __restrict__ cbf,
                 const float* __restrict__ c2,
                 float* __restrict__ out_idx,
                 float* __restrict__ out_dist) {
    __shared__ __align__(16) float c2s[K_CENT];
    int tid = threadIdx.x;
    c2s[tid] = c2[tid];
    c2s[tid + 256] = c2[tid + 256];
    __syncthreads();

    int wave = tid >> 6;
    int lane = tid & 63;
    int l15  = lane & 15;
    int grp  = lane >> 4;        // 0..3
    int grp4 = grp * 4;
    int grp8 = grp * 8;

    int job = blockIdx.x * 4 + wave;
    if (job >= N_JOBS) return;
    int sub0 = job * 3;          // first 16-point subtile index

    // ---- load + convert X: 3 point-subtiles x 2 K-steps, 8 dims/lane each
    half8 bh[3][2], bl[3][2];
    float x2[3] = {0.f, 0.f, 0.f};
#pragma unroll
    for (int ps = 0; ps < 3; ++ps) {
        int p = (sub0 + ps) * 16 + l15;
        int pe = p < N_POINTS ? p : (N_POINTS - 1);
#pragma unroll
        for (int ks = 0; ks < 2; ++ks) {
            const float4* xp = (const float4*)(X + (size_t)pe * W_DIM + ks * 32 + grp8);
            float4 f0 = xp[0], f1 = xp[1];
            float fa[8] = {f0.x, f0.y, f0.z, f0.w, f1.x, f1.y, f1.z, f1.w};
#pragma unroll
            for (int j = 0; j < 8; ++j) {
                _Float16 hh = (_Float16)fa[j];
                bh[ps][ks][j] = hh;
                bl[ps][ks][j] = (_Float16)(fa[j] - (float)hh);
                x2[ps] = fmaf(fa[j], fa[j], x2[ps]);
            }
        }
    }
#pragma unroll
    for (int ps = 0; ps < 3; ++ps) {    // full ||x||^2 across the 4 row-groups
        x2[ps] += __shfl_xor(x2[ps], 16);
        x2[ps] += __shfl_xor(x2[ps], 32);
    }

    float bd[3] = {3.4e38f, 3.4e38f, 3.4e38f};
    int   bi[3] = {0, 0, 0};

    f32x4 q0, q1;
    f32x4 accP[2][3], accQ[2][3];              // P/Q acc double-buffer
    half8 ahA[2][2], alA[2][2], ahB[2][2], alB[2][2];

    PREFETCH_A(0, ahA, alA)
    q0 = *(const f32x4*)&c2s[0 * 16 + grp4];
    q1 = *(const f32x4*)&c2s[1 * 16 + grp4];

    // chunk 0 (buf A -> accP); prefetch A(1)->B, q(1)
    MFMA_CHUNK(0, ahA, alA, ahB, alB, accP)

#pragma unroll 1
    for (int tt = 0; tt < 7; ++tt) {
        MFMA_CHUNK(2 * tt + 1, ahB, alB, ahA, alA, accQ)
        ARGMIN_CHUNK(2 * tt, accP)
        MFMA_CHUNK(2 * tt + 2, ahA, alA, ahB, alB, accP)
        ARGMIN_CHUNK(2 * tt + 1, accQ)
    }
    MFMA_CHUNK(15, ahB, alB, ahA, alA, accQ)
    ARGMIN_CHUNK(14, accP)
    ARGMIN_CHUNK(15, accQ)

    // cross-lane combine over the 4 row-groups (disjoint cents per group);
    // explicit lower-index preference on fp-equal ties.
#pragma unroll
    for (int ps = 0; ps < 3; ++ps) {
        float od = __shfl_xor(bd[ps], 16); int oi = __shfl_xor(bi[ps], 16);
        if (od < bd[ps] || (od == bd[ps] && oi < bi[ps])) { bd[ps] = od; bi[ps] = oi; }
        od = __shfl_xor(bd[ps], 32); oi = __shfl_xor(bi[ps], 32);
        if (od < bd[ps] || (od == bd[ps] && oi < bi[ps])) { bd[ps] = od; bi[ps] = oi; }
    }

    if (grp == 0) {
#pragma unroll
        for (int ps = 0; ps < 3; ++ps) {
            int p = (sub0 + ps) * 16 + l15;
            if (p < N_POINTS) {
                out_idx[p]  = (float)bi[ps];
                out_dist[p] = sqrtf(fmaxf(bd[ps] + x2[ps], 0.f));
            }
        }
    }
}

extern "C" void kernel_launch(void* const* d_in, const int* in_sizes, int n_in,
                              void* d_out, int out_size, void* d_ws, size_t ws_size,
                              hipStream_t stream) {
    const float* X  = (const float*)d_in[0];
    const float* cb = (const float*)d_in[1];
    float* out      = (float*)d_out;

    // workspace: fragment-ordered codebook 128KB | c2 2KB
    _Float16* cbf = (_Float16*)d_ws;
    float*    c2  = (float*)(cbf + (size_t)K_CENT * W_DIM * 2);

    hipLaunchKernelGGL(cvt_kernel, dim3((K_CENT * 8 + 255) / 256), dim3(256), 0, stream, cb, cbf);
    hipLaunchKernelGGL(c2_kernel, dim3((K_CENT + 255) / 256), dim3(256), 0, stream, cb, c2);

    hipLaunchKernelGGL(kmeans_mfma, dim3((N_JOBS + 3) / 4), dim3(256), 0, stream,
                       X, cbf, c2, out, out + N_POINTS);
}